// Round 1
// baseline (159.439 us; speedup 1.0000x reference)
//
#include <hip/hip_runtime.h>

#define BINS 4096            // 64 * 64
#define HIST_BLOCKS 512
#define HIST_THREADS 1024    // 16 waves/block * 2 blocks/CU = 32 waves/CU (100% occ)

#define RED_TPB 256
#define RED_BG  (BINS / RED_TPB)   // 16 bin-groups of 256 bins
#define RED_PG  16                 // 16 partial-groups -> grid 256, 16-way atomic contention

// out[i] = transitions_in[i] for i < bins; out[bins] = total_in + n_events
__global__ void topo_init_kernel(const float* __restrict__ transitions,
                                 const float* __restrict__ total,
                                 float* __restrict__ out,
                                 float n_events_f, int bins) {
    int i = blockIdx.x * blockDim.x + threadIdx.x;
    if (i < bins) out[i] = transitions[i];
    if (i == 0) out[bins] = total[0] + n_events_f;
}

__global__ void __launch_bounds__(HIST_THREADS)
topo_hist_kernel(const int* __restrict__ prev,
                 const int* __restrict__ curr,
                 float* __restrict__ out,
                 unsigned int* __restrict__ ws,
                 int n, int use_ws) {
    __shared__ unsigned int h[BINS];
    for (int i = threadIdx.x; i < BINS; i += HIST_THREADS) h[i] = 0u;
    __syncthreads();

    const int n4 = n >> 2;
    const int4* __restrict__ p4 = (const int4*)prev;
    const int4* __restrict__ c4 = (const int4*)curr;

    // Grid-stride with 2x unroll: 4 dwordx4 loads in flight per lane before the
    // LDS atomic burst (LDS atomics are add-without-return: no wave stall).
    const int base   = blockIdx.x * (HIST_THREADS * 2) + threadIdx.x;
    const int stride = gridDim.x * (HIST_THREADS * 2);

    for (int i = base; i < n4; i += stride) {
        const int j = i + HIST_THREADS;
        int4 p0 = p4[i];
        int4 c0 = c4[i];
        int4 p1, c1;
        const bool ok = (j < n4);
        if (ok) { p1 = p4[j]; c1 = c4[j]; }

        atomicAdd(&h[(p0.x << 6) | c0.x], 1u);
        atomicAdd(&h[(p0.y << 6) | c0.y], 1u);
        atomicAdd(&h[(p0.z << 6) | c0.z], 1u);
        atomicAdd(&h[(p0.w << 6) | c0.w], 1u);
        if (ok) {
            atomicAdd(&h[(p1.x << 6) | c1.x], 1u);
            atomicAdd(&h[(p1.y << 6) | c1.y], 1u);
            atomicAdd(&h[(p1.z << 6) | c1.z], 1u);
            atomicAdd(&h[(p1.w << 6) | c1.w], 1u);
        }
    }
    // tail (n not divisible by 4 — not hit for 16.7M but kept for safety)
    for (int i = (n4 << 2) + blockIdx.x * HIST_THREADS + threadIdx.x; i < n;
         i += gridDim.x * HIST_THREADS) {
        atomicAdd(&h[(prev[i] << 6) | curr[i]], 1u);
    }

    __syncthreads();

    if (use_ws) {
        // Private per-block partial: plain coalesced dwordx4 stores, ZERO atomics.
        // 1024 threads x 1 uint4 = 4096 bins. No same-address contention at all.
        uint4* __restrict__ dst = (uint4*)(ws + (size_t)blockIdx.x * BINS);
        for (int t = threadIdx.x; t < (BINS >> 2); t += HIST_THREADS) {
            dst[t] = *reinterpret_cast<const uint4*>(&h[t << 2]);
        }
    } else {
        // Fallback (workspace too small): old contended float-atomic flush.
        for (int i = threadIdx.x; i < BINS; i += HIST_THREADS) {
            unsigned int c = h[i];
            if (c) atomicAdd(&out[i], (float)c);
        }
    }
}

// Sum the per-block partials. blockIdx = pg * RED_BG + bg.
// Thread handles one bin; reads are coalesced across threads (row-major partials).
// Final atomics: RED_PG-way contention per bin only (64K atomics total).
__global__ void __launch_bounds__(RED_TPB)
topo_reduce_kernel(const unsigned int* __restrict__ ws,
                   float* __restrict__ out, int nparts) {
    const int bg  = blockIdx.x % RED_BG;
    const int pg  = blockIdx.x / RED_BG;
    const int bin = bg * RED_TPB + threadIdx.x;

    const int pp = (nparts + RED_PG - 1) / RED_PG;
    const int p0 = pg * pp;
    const int p1 = (p0 + pp < nparts) ? (p0 + pp) : nparts;

    unsigned int s = 0;
    for (int p = p0; p < p1; ++p) s += ws[(size_t)p * BINS + bin];
    if (s) atomicAdd(&out[bin], (float)s);
}

extern "C" void kernel_launch(void* const* d_in, const int* in_sizes, int n_in,
                              void* d_out, int out_size, void* d_ws, size_t ws_size,
                              hipStream_t stream) {
    const int*   prev        = (const int*)d_in[0];
    const int*   curr        = (const int*)d_in[1];
    const float* transitions = (const float*)d_in[2];
    const float* total       = (const float*)d_in[3];
    float* out = (float*)d_out;

    const int n    = in_sizes[0];
    const int bins = in_sizes[2];   // 4096

    const size_t ws_needed = (size_t)HIST_BLOCKS * BINS * sizeof(unsigned int);
    const int use_ws = (d_ws != nullptr && ws_size >= ws_needed) ? 1 : 0;

    // 1) initialize output: copy transitions input, set total = total_in + n
    int init_blocks = (bins + 1 + 255) / 256;
    topo_init_kernel<<<init_blocks, 256, 0, stream>>>(transitions, total, out,
                                                      (float)n, bins);

    // 2) per-block LDS histogram; flush = private partial stores (no atomics)
    topo_hist_kernel<<<HIST_BLOCKS, HIST_THREADS, 0, stream>>>(
        prev, curr, out, (unsigned int*)d_ws, n, use_ws);

    // 3) reduce partials into out (16-way-contended atomics only)
    if (use_ws) {
        topo_reduce_kernel<<<RED_BG * RED_PG, RED_TPB, 0, stream>>>(
            (const unsigned int*)d_ws, out, HIST_BLOCKS);
    }
}